// Round 12
// baseline (89.002 us; speedup 1.0000x reference)
//
#include <hip/hip_runtime.h>
#include <hip/hip_bf16.h>

// out[t,z] = sum_i f[t,i] * ( sum_j a[t,j] * C[i,j,z] )
// R12 = R10 barrier-free fragment-major K-loop, wave tile 32x16, occupancy 16
// waves/CU (launch_bounds(256,4), live regs ~103 <= 128 cap, no spill).
// Occupancy is the only lever with measured scaling (8->12 waves: 43->26 us).
// Block 4 waves (2 mg x 2 zg) = 64 rows x 32 z. Grid 2048 = 64mt x 4zp x 8kp.
// kp=bid&7 -> XCD-affine CT chunk (fits L2 regardless).
// ws: [0,16MB) fp32 partials [kp][4096][128]; [16,20MB) CTf; [20,21MB) APK.
//  CTf[i][z>>4][j>>3][z&15][j&7] bf16 ; APK[t>>4][ks][lk][lm][8k] bf16 —
//  every hot wave-load is ONE contiguous 1 KB segment (base + lane*16).

typedef __attribute__((ext_vector_type(8))) short bf16x8;
typedef __attribute__((ext_vector_type(4))) float f32x4;

__device__ __forceinline__ unsigned pkbf16(float x, float y) {
    __hip_bfloat162 h = __float22bfloat162_rn(make_float2(x, y));
    unsigned u; __builtin_memcpy(&u, &h, sizeof(u));
    return u;
}

// ---------- prep: transpose C->CTf (bid<512) + pack a->APK (bid>=512) ----------
__global__ __launch_bounds__(256) void cooc_prep(
    const float* __restrict__ Cc, const float* __restrict__ fa,
    ushort* __restrict__ CT, ushort* __restrict__ APK)
{
    const int bid = blockIdx.x;
    const int t = threadIdx.x;
    if (bid < 512) {
        __shared__ float tile[32][132];
        const int i  = bid >> 2;
        const int j0 = (bid & 3) * 32;
        {
            const int jj = t >> 3;
            const int zb = (t & 7) * 16;
            const float* src = Cc + (size_t)i * 16384 + (size_t)(j0 + jj) * 128 + zb;
            #pragma unroll
            for (int k = 0; k < 4; ++k)
                *(float4*)&tile[jj][zb + k * 4] = *(const float4*)(src + k * 4);
        }
        __syncthreads();
        {
            const int z = t >> 1;
            const int h = t & 1;
            unsigned o[8];
            #pragma unroll
            for (int p = 0; p < 8; ++p)
                o[p] = pkbf16(tile[h * 16 + 2 * p][z], tile[h * 16 + 2 * p + 1][z]);
            const int c0 = (j0 >> 3) + h * 2;
            ushort* dst = CT + (size_t)i * 16384 + (size_t)(z >> 4) * 2048
                             + (size_t)c0 * 128 + (z & 15) * 8;
            *(uint4*)dst         = make_uint4(o[0], o[1], o[2], o[3]);
            *(uint4*)(dst + 128) = make_uint4(o[4], o[5], o[6], o[7]);
        }
    } else {
        const int g = bid - 512;           // 0..255: 16-row group
        const int ks = t >> 6, lk = (t >> 4) & 3, lm = t & 15;
        const float* src = fa + (size_t)(g * 16 + lm) * 256 + 128 + ks * 32 + lk * 8;
        float4 q0 = *(const float4*)src;
        float4 q1 = *(const float4*)(src + 4);
        *(uint4*)(APK + (size_t)g * 2048 + t * 8) =
            make_uint4(pkbf16(q0.x, q0.y), pkbf16(q0.z, q0.w),
                       pkbf16(q1.x, q1.y), pkbf16(q1.z, q1.w));
    }
}

// ---------- main ----------
template<int USE_WS>
__global__ __launch_bounds__(256, 4) void cooc_main(
    const float* __restrict__ fa, const ushort* __restrict__ CT,
    const ushort* __restrict__ APK, float* __restrict__ dst)
{
    __shared__ float f_lds[16][64];        // 4 KB: f[i_local][row]

    const int bid = blockIdx.x;
    const int kp = bid & 7, zp = (bid >> 3) & 3, mtile = bid >> 5;   // mt 0..63
    const int t0 = mtile * 64, i0 = kp * 16;
    const int tid = threadIdx.x, lane = tid & 63, wv = tid >> 6;
    const int mg = wv >> 1, zg = wv & 1;   // 32-row group, 16-z group
    const int lm = lane & 15, lk = lane >> 4;

    // stage f -> LDS (transposed [i][row]): 64 rows x 16 i, 4 vals/thread
    {
        const int row = tid & 63;
        const int sh = (tid >> 6) * 4;     // 0,4,8,12
        const float* fp = fa + (size_t)(t0 + row) * 256 + i0 + sh;
        float4 v = *(const float4*)fp;
        f_lds[sh + 0][row] = v.x;
        f_lds[sh + 1][row] = v.y;
        f_lds[sh + 2][row] = v.z;
        f_lds[sh + 3][row] = v.w;
    }

    // A fragments: 8 contiguous 1 KB wave-loads (rows t0 + mg*32 .. +31)
    bf16x8 a_pk[2][2][4];                  // [unused-sym m][..] -> 32 regs total
    {
        const ushort* ap = APK + (size_t)((t0 >> 4) + mg * 2) * 2048 + lane * 8;
        #pragma unroll
        for (int m = 0; m < 2; ++m)
            #pragma unroll
            for (int ks = 0; ks < 4; ++ks) {
                a_pk[0][m][ks] = *(const bf16x8*)(ap + (size_t)m * 2048 + ks * 512);
                a_pk[1][m][ks] = a_pk[0][m][ks];   // folded by regalloc (aliases)
            }
    }
    __syncthreads();   // f_lds ready; only barrier

    // B source (contiguous): CTf + i*16384 + (zp*2+zg)*2048 + lane*8
    const ushort* bsrc = CT + (size_t)i0 * 16384
                            + (size_t)(zp * 2 + zg) * 2048 + lane * 8;

    // prime depth-2 prefetch: s=0 -> B[0], s=1 -> B[1]
    bf16x8 B[2][4];
    #pragma unroll
    for (int ks = 0; ks < 4; ++ks) {
        B[0][ks] = *(const bf16x8*)(bsrc + ks * 512);
        B[1][ks] = *(const bf16x8*)(bsrc + 16384 + ks * 512);
    }

    float acc[2][4];
    #pragma unroll
    for (int m = 0; m < 2; ++m)
        #pragma unroll
        for (int r = 0; r < 4; ++r) acc[m][r] = 0.f;

    #pragma unroll 2
    for (int s = 0; s < 16; ++s) {
        const int cur = s & 1;

        // 2 independent MFMA chains, ks-outer (dep distance 2)
        f32x4 g[2];
        g[0] = (f32x4){0.f, 0.f, 0.f, 0.f};
        g[1] = (f32x4){0.f, 0.f, 0.f, 0.f};
        #pragma unroll
        for (int ks = 0; ks < 4; ++ks) {
            g[0] = __builtin_amdgcn_mfma_f32_16x16x32_bf16(
                a_pk[0][0][ks], B[cur][ks], g[0], 0, 0, 0);
            g[1] = __builtin_amdgcn_mfma_f32_16x16x32_bf16(
                a_pk[0][1][ks], B[cur][ks], g[1], 0, 0, 0);
        }

        // reload B[cur] with slab s+2 (issued after consumption; ~2-slab cover)
        if (s < 14) {
            const ushort* p = bsrc + (size_t)(s + 2) * 16384;
            #pragma unroll
            for (int ks = 0; ks < 4; ++ks)
                B[cur][ks] = *(const bf16x8*)(p + ks * 512);
        }

        // f read + fold
        float4 f4[2];
        f4[0] = *(const float4*)&f_lds[s][mg * 32 + lk * 4];
        f4[1] = *(const float4*)&f_lds[s][mg * 32 + 16 + lk * 4];
        #pragma unroll
        for (int m = 0; m < 2; ++m) {
            acc[m][0] += f4[m].x * g[m][0];
            acc[m][1] += f4[m].y * g[m][1];
            acc[m][2] += f4[m].z * g[m][2];
            acc[m][3] += f4[m].w * g[m][3];
        }
    }

    // epilogue: C/D col=lm, row=lk*4+r
    const int col = zp * 32 + zg * 16 + lm;
    #pragma unroll
    for (int m = 0; m < 2; ++m)
        #pragma unroll
        for (int r = 0; r < 4; ++r) {
            const int row = t0 + mg * 32 + m * 16 + lk * 4 + r;
            if (USE_WS)
                dst[(size_t)kp * 524288 + (size_t)row * 128 + col] = acc[m][r];
            else
                atomicAdd(&dst[(size_t)row * 128 + col], acc[m][r]);
        }
}

__global__ __launch_bounds__(256) void cooc_reduce(const float* __restrict__ ws,
                                                   float* __restrict__ out) {
    const size_t idx = ((size_t)blockIdx.x * 256 + threadIdx.x) * 4;
    float4 a = *(const float4*)(ws + idx);
    #pragma unroll
    for (int k = 1; k < 8; ++k) {
        float4 b = *(const float4*)(ws + (size_t)k * 524288 + idx);
        a.x += b.x; a.y += b.y; a.z += b.z; a.w += b.w;
    }
    *(float4*)(out + idx) = a;
}

extern "C" void kernel_launch(void* const* d_in, const int* in_sizes, int n_in,
                              void* d_out, int out_size, void* d_ws, size_t ws_size,
                              hipStream_t stream) {
    const float* fa = (const float*)d_in[0];   // (4096,256): [:,0:128]=f, [:,128:256]=a
    const float* Cc = (const float*)d_in[1];   // (128,128,128)
    float* out = (float*)d_out;                // (4096,128)

    const size_t PART = (size_t)8 * 524288;                  // fp32 partials: 16 MiB
    const size_t CTOF = PART * sizeof(float);                // 16 MiB
    const size_t CTSZ = (size_t)128 * 128 * 128 * 2;         // 4 MiB
    const size_t APOF = CTOF + CTSZ;                         // 20 MiB
    const size_t APSZ = (size_t)4096 * 128 * 2;              // 1 MiB
    const size_t NEED_FULL = APOF + APSZ;
    const size_t NEED_CT   = CTSZ + APSZ;

    if (ws_size >= NEED_FULL) {
        ushort* CT  = (ushort*)((char*)d_ws + CTOF);
        ushort* APK = (ushort*)((char*)d_ws + APOF);
        cooc_prep<<<768, 256, 0, stream>>>(Cc, fa, CT, APK);
        cooc_main<1><<<2048, 256, 0, stream>>>(fa, CT, APK, (float*)d_ws);
        cooc_reduce<<<512, 256, 0, stream>>>((const float*)d_ws, out);
    } else if (ws_size >= NEED_CT) {
        ushort* CT  = (ushort*)d_ws;
        ushort* APK = (ushort*)((char*)d_ws + CTSZ);
        cooc_prep<<<768, 256, 0, stream>>>(Cc, fa, CT, APK);
        (void)hipMemsetAsync(out, 0, (size_t)out_size * sizeof(float), stream);
        cooc_main<0><<<2048, 256, 0, stream>>>(fa, CT, APK, out);
    } else {
        (void)hipMemsetAsync(out, 0, (size_t)out_size * sizeof(float), stream);
        cooc_main<0><<<2048, 256, 0, stream>>>(fa, (const ushort*)d_ws,
                                               (const ushort*)d_ws, out);
    }
}